// Round 1
// baseline (62.014 us; speedup 1.0000x reference)
//
#include <hip/hip_runtime.h>

#define D_DIM 4096
#define EPSF 1e-8f

// One block per row. 256 threads x 4 float4 = 4096 floats per tensor.
__global__ __launch_bounds__(256) void cosim_rows(const float* __restrict__ q,
                                                  const float* __restrict__ a,
                                                  float* __restrict__ cos_out) {
    const int row = blockIdx.x;
    const int t = threadIdx.x;
    const float4* q4 = reinterpret_cast<const float4*>(q + (size_t)row * D_DIM);
    const float4* a4 = reinterpret_cast<const float4*>(a + (size_t)row * D_DIM);

    float dot = 0.f, qq = 0.f, aa = 0.f;
#pragma unroll
    for (int k = 0; k < 4; ++k) {
        float4 vq = q4[t + k * 256];
        float4 va = a4[t + k * 256];
        dot += vq.x * va.x + vq.y * va.y + vq.z * va.z + vq.w * va.w;
        qq  += vq.x * vq.x + vq.y * vq.y + vq.z * vq.z + vq.w * vq.w;
        aa  += va.x * va.x + va.y * va.y + va.z * va.z + va.w * va.w;
    }

    // wave64 butterfly-free down-reduce (lane 0 of each wave holds the sum)
#pragma unroll
    for (int off = 32; off > 0; off >>= 1) {
        dot += __shfl_down(dot, off, 64);
        qq  += __shfl_down(qq,  off, 64);
        aa  += __shfl_down(aa,  off, 64);
    }

    __shared__ float s[3][4];
    const int wave = t >> 6;
    if ((t & 63) == 0) { s[0][wave] = dot; s[1][wave] = qq; s[2][wave] = aa; }
    __syncthreads();
    if (t == 0) {
        float d   = s[0][0] + s[0][1] + s[0][2] + s[0][3];
        float qsq = s[1][0] + s[1][1] + s[1][2] + s[1][3];
        float asq = s[2][0] + s[2][1] + s[2][2] + s[2][3];
        float qn = fmaxf(sqrtf(qsq), EPSF);
        float an = fmaxf(sqrtf(asq), EPSF);
        cos_out[row] = d / (qn * an);
    }
}

// Single block: deterministic reduction of cos values split by label, then loss.
__global__ __launch_bounds__(256) void cosim_finalize(const float* __restrict__ cosv,
                                                      const int* __restrict__ label,
                                                      const float* __restrict__ margin,
                                                      float* __restrict__ out, int B) {
    const int t = threadIdx.x;
    float ts = 0.f, fs = 0.f, tc = 0.f, fc = 0.f;
    for (int i = t; i < B; i += 256) {
        float c = cosv[i];
        int l = label[i];
        if (l == 1)       { ts += c; tc += 1.f; }
        else if (l == -1) { fs += c; fc += 1.f; }
    }
#pragma unroll
    for (int off = 32; off > 0; off >>= 1) {
        ts += __shfl_down(ts, off, 64);
        fs += __shfl_down(fs, off, 64);
        tc += __shfl_down(tc, off, 64);
        fc += __shfl_down(fc, off, 64);
    }
    __shared__ float s[4][4];
    const int wave = t >> 6;
    if ((t & 63) == 0) { s[0][wave] = ts; s[1][wave] = fs; s[2][wave] = tc; s[3][wave] = fc; }
    __syncthreads();
    if (t == 0) {
        float tsum = s[0][0] + s[0][1] + s[0][2] + s[0][3];
        float fsum = s[1][0] + s[1][1] + s[1][2] + s[1][3];
        float tcnt = s[2][0] + s[2][1] + s[2][2] + s[2][3];
        float fcnt = s[3][0] + s[3][1] + s[3][2] + s[3][3];
        float true_ave  = tsum / tcnt;
        float false_ave = fsum / fcnt;
        out[0] = fmaxf(0.f, margin[0] - true_ave + false_ave);
    }
}

extern "C" void kernel_launch(void* const* d_in, const int* in_sizes, int n_in,
                              void* d_out, int out_size, void* d_ws, size_t ws_size,
                              hipStream_t stream) {
    const float* ques   = (const float*)d_in[0];
    const float* ans    = (const float*)d_in[1];
    const int*   label  = (const int*)d_in[2];
    const float* margin = (const float*)d_in[3];
    float* out = (float*)d_out;

    const int B = in_sizes[2];          // 8192 rows (label is B x 1)
    float* cosv = (float*)d_ws;         // B floats of scratch

    cosim_rows<<<B, 256, 0, stream>>>(ques, ans, cosv);
    cosim_finalize<<<1, 256, 0, stream>>>(cosv, label, margin, out, B);
}